// Round 7
// baseline (26645.065 us; speedup 1.0000x reference)
//
#include <hip/hip_runtime.h>
#include <stdint.h>
#include <stddef.h>

// LSTMNetwork: 3-layer stacked LSTM, batch=1, T=4096, IN=64, H=1024, OUT=1.
//
// Round 15: halve hot-line readers and producer stragglers again.
//   Evidence chain: R12 (+768 readers/line -> +3.2us/step), R14 (-128
//   readers -> -0.5us). Readers/line during the publish window is the
//   addressable term; bytes (R11) and barriers (R12) are not.
//   XCD-local exchange is structurally impossible: one layer's register-
//   resident W_hh = 4.19M regs = exactly one XCD's total VGPR capacity,
//   so the h self-loop must cross the LLC. Pressure is the only lever.
//   Change vs R14 (per-wave code byte-identical -- proven 84 VGPR + AGPR
//   shape, 2 units/wave):
//     - 512-thread blocks (8 waves), 16 units/block => 64 h-blocks/layer
//       (was 128). Hot-line readers 128->64, straggler pool 128->64.
//     - x-role likewise 64 blocks/layer (reads mirrors, as R14).
//     - h-poll gentle backoff s_sleep(2) (~53ns) after 2 failed rounds;
//       x keeps s_sleep(4) from round 1.
//   Co-residency: 320 blocks; __launch_bounds__(512,3) caps ~170 regs/wave;
//   h-blocks cannot stack (2/SIMD x 170 = 340), x packs beside (508<=512).
//   Exchange: 64-bit tagged slots, relaxed agent atomics, no fences.

#define T_STEPS 4096
#define HD      1024
#define RINGR   16
#define NBH     64          // h-blocks (and x-blocks) per layer

#define TAGL0 0x10000000u
#define TAGL1 0x30000000u
#define TAGL2 0x50000000u
#define TAGP1 0x70000000u
#define TAGP2 0x90000000u

typedef unsigned long long u64;
typedef uint32_t u32;

// Module .bss (~448 MB). Harness never pokes these.
__device__ u64 g_bufA[(size_t)T_STEPS * HD];    // layer0 h history (32 MB)
__device__ u64 g_bufB[(size_t)T_STEPS * HD];    // layer1 h history (32 MB)
__device__ u64 g_ring[RINGR * HD];              // layer2 h ring (128 KB)
__device__ u64 g_mirA[(size_t)T_STEPS * HD];    // layer0 h mirror for x-readers (32 MB)
__device__ u64 g_mirB[(size_t)T_STEPS * HD];    // layer1 h mirror for x-readers (32 MB)
__device__ u64 g_pre1[(size_t)T_STEPS * 4096];  // layer1 gate preacts (128 MB)
__device__ u64 g_pre2[(size_t)T_STEPS * 4096];  // layer2 gate preacts (128 MB)

__device__ __forceinline__ float fsig(float x)  { return 1.0f / (1.0f + __expf(-x)); }
__device__ __forceinline__ float ftanh(float x) { return 1.0f - 2.0f / (__expf(2.0f * x) + 1.0f); }

__global__ __launch_bounds__(256)
void zero_bufs()
{
    const size_t gtid = (size_t)blockIdx.x * blockDim.x + threadIdx.x;
    const size_t step = (size_t)gridDim.x * blockDim.x;
    const size_t nh = (size_t)T_STEPS * HD;
    for (size_t i = gtid; i < nh; i += step) {
        g_bufA[i] = 0ULL; g_bufB[i] = 0ULL; g_mirA[i] = 0ULL; g_mirB[i] = 0ULL;
    }
    for (size_t i = gtid; i < (size_t)RINGR * HD; i += step) g_ring[i] = 0ULL;
}

__global__ __launch_bounds__(512, 3)   // 320 blocks; 170-reg cap => all co-resident
void fused_scan(const float* __restrict__ seq,
                const float* __restrict__ wih0, const float* __restrict__ whh0_,
                const float* __restrict__ bih0, const float* __restrict__ bhh0,
                const float* __restrict__ wih1, const float* __restrict__ whh1_,
                const float* __restrict__ bih1, const float* __restrict__ bhh1,
                const float* __restrict__ wih2, const float* __restrict__ whh2_,
                const float* __restrict__ bih2, const float* __restrict__ bhh2)
{
    __shared__ float s_buf[2][HD];   // staged source row (own-h for h-role, upstream-h for x-role)

    const int bid  = blockIdx.x;
    const int lane = threadIdx.x & 63;
    const int wave = threadIdx.x >> 6;           // 0..7

    const bool isH  = (bid < 3 * NBH);
    const int layer = isH ? (bid / NBH) : (1 + ((bid - 3 * NBH) >> 6));
    const int bu    = isH ? (bid & (NBH - 1)) : ((bid - 3 * NBH) & (NBH - 1));
    const int j0    = bu * 16 + wave * 2;        // first of this wave's 2 units
    const int k     = lane & 7;                  // acc index this lane finalizes (u*4+g)
    const int rk    = ((k & 3) << 10) + j0 + (k >> 2);   // its gate-row in [4H]

    // ---- role pointers ----
    const float* Wmat;
    const u64*  srcVal;  uint32_t srcTagB, srcRowM = 0xFFFFFFFFu;
    u64*        valOut = nullptr;   u64* mirOut = nullptr;
    u64*        preOut = nullptr;
    const u64*  preIn  = nullptr;
    uint32_t    myTagB = 0, preTagB = 0;
    float       biasL  = 0.f;

    if (isH) {
        Wmat    = (layer == 0) ? whh0_ : (layer == 1) ? whh1_ : whh2_;
        valOut  = (layer == 0) ? g_bufA : (layer == 1) ? g_bufB : g_ring;
        mirOut  = (layer == 0) ? g_mirA : (layer == 1) ? g_mirB : nullptr;
        myTagB  = (layer == 0) ? TAGL0 : (layer == 1) ? TAGL1 : TAGL2;
        srcRowM = (layer == 2) ? (RINGR - 1) : 0xFFFFFFFFu;
        srcVal  = valOut; srcTagB = myTagB;      // own history
        if (layer == 1) { preIn = g_pre1; preTagB = TAGP1; }
        if (layer == 2) { preIn = g_pre2; preTagB = TAGP2; }
        if (layer == 0) biasL = bih0[rk] + bhh0[rk];
    } else {
        Wmat    = (layer == 1) ? wih1 : wih2;
        srcVal  = (layer == 1) ? g_mirA : g_mirB;           // read the MIRROR
        srcTagB = (layer == 1) ? TAGL0 : TAGL1;
        preOut  = (layer == 1) ? g_pre1 : g_pre2;
        preTagB = (layer == 1) ? TAGP1 : TAGP2;
        biasL   = (layer == 1) ? (bih1[rk] + bhh1[rk]) : (bih2[rk] + bhh2[rk]);
    }

    // ---- weights into registers: 8 gate-rows (2 units x 4 gates) x 16 ----
    float W[8][16];
#pragma unroll
    for (int u = 0; u < 2; ++u)
#pragma unroll
        for (int g = 0; g < 4; ++g) {
            const float* pr = Wmat + (size_t)((g << 10) + j0 + u) * HD;
#pragma unroll
            for (int i = 0; i < 16; ++i) W[u * 4 + g][i] = pr[(i << 6) + lane];
        }

    float wi0[8];
    if (isH && layer == 0) {
#pragma unroll
        for (int kk = 0; kk < 8; ++kk)
            wi0[kk] = wih0[(size_t)(((kk & 3) << 10) + j0 + (kk >> 2)) * 64 + lane];
    }

    float c = 0.f;
    const int sb = wave << 7;    // this wave's staging eighth: [sb, sb+128)

    for (int t = 0; t < T_STEPS; ++t) {
        const int p = t & 1;
        u64 pre = 0; float xv = 0.f;
        const bool needRow = (!isH) || (t > 0);

        // ---- early preact probe (one line, >=1 pipeline slot of slack) ----
        if (isH) {
            if (layer == 0) {
                xv = seq[(size_t)t * 64 + lane];
            } else {
                pre = __hip_atomic_load(preIn + (size_t)t * 4096 + (j0 << 2) + k,
                                        __ATOMIC_RELAXED, __HIP_MEMORY_SCOPE_AGENT);
            }
        }

        // ---- staging: poll own eighth (2 groups), stage incrementally ----
        if (needRow) {
            const uint32_t stag = srcTagB + (uint32_t)(isH ? (t - 1) : t);
            const u64* rowp = srcVal
                + (size_t)((uint32_t)(isH ? (t - 1) : t) & srcRowM) * HD;
            u32 todo = 0x3u;
            int round = 0;
            while (__any(todo)) {
                if (!isH) { if (round >= 1) __builtin_amdgcn_s_sleep(4); }   // ~107ns
                else      { if (round >= 2) __builtin_amdgcn_s_sleep(2); }   // ~53ns
#pragma unroll
                for (int i = 0; i < 2; ++i) if (todo & (1u << i)) {
                    const u64 u = __hip_atomic_load(rowp + sb + (i << 6) + lane,
                                                    __ATOMIC_RELAXED, __HIP_MEMORY_SCOPE_AGENT);
                    if ((uint32_t)(u >> 32) == stag) {
                        s_buf[p][sb + (i << 6) + lane] = __uint_as_float((uint32_t)u);
                        todo &= ~(1u << i);
                    }
                }
                ++round;
            }
        }
        __syncthreads();

        // ---- 8 gate dot-products (per-lane partials) ----
        float a0, a1, a2, a3, a4, a5, a6, a7;
        if (isH && layer == 0) {
            a0 = wi0[0] * xv; a1 = wi0[1] * xv; a2 = wi0[2] * xv; a3 = wi0[3] * xv;
            a4 = wi0[4] * xv; a5 = wi0[5] * xv; a6 = wi0[6] * xv; a7 = wi0[7] * xv;
        } else {
            a0 = a1 = a2 = a3 = a4 = a5 = a6 = a7 = 0.f;
        }
        if (needRow) {
            const float* sp = s_buf[p];
#pragma unroll
            for (int i = 0; i < 16; ++i) {
                const float hv = sp[(i << 6) | lane];
                a0 = __fmaf_rn(W[0][i], hv, a0);
                a1 = __fmaf_rn(W[1][i], hv, a1);
                a2 = __fmaf_rn(W[2][i], hv, a2);
                a3 = __fmaf_rn(W[3][i], hv, a3);
                a4 = __fmaf_rn(W[4][i], hv, a4);
                a5 = __fmaf_rn(W[5][i], hv, a5);
                a6 = __fmaf_rn(W[6][i], hv, a6);
                a7 = __fmaf_rn(W[7][i], hv, a7);
            }
        }

        // ---- scatter-butterfly reduce: lane l ends with 64-lane sum of acc (l&7) ----
        float e;
        {
            const int l1 = lane & 1, l2 = lane & 2, l4 = lane & 4;
            const float s0 = __shfl_xor(a0, 1, 64), s1 = __shfl_xor(a1, 1, 64);
            const float s2 = __shfl_xor(a2, 1, 64), s3 = __shfl_xor(a3, 1, 64);
            const float s4 = __shfl_xor(a4, 1, 64), s5 = __shfl_xor(a5, 1, 64);
            const float s6 = __shfl_xor(a6, 1, 64), s7 = __shfl_xor(a7, 1, 64);
            const float c0 = l1 ? (a1 + s1) : (a0 + s0);
            const float c1 = l1 ? (a3 + s3) : (a2 + s2);
            const float c2 = l1 ? (a5 + s5) : (a4 + s4);
            const float c3 = l1 ? (a7 + s7) : (a6 + s6);
            const float u0 = __shfl_xor(c0, 2, 64), u1 = __shfl_xor(c1, 2, 64);
            const float u2 = __shfl_xor(c2, 2, 64), u3 = __shfl_xor(c3, 2, 64);
            const float d0 = l2 ? (c1 + u1) : (c0 + u0);
            const float d1 = l2 ? (c3 + u3) : (c2 + u2);
            const float v0 = __shfl_xor(d0, 4, 64), v1 = __shfl_xor(d1, 4, 64);
            e = l4 ? (d1 + v1) : (d0 + v0);
            e += __shfl_xor(e, 8, 64);
            e += __shfl_xor(e, 16, 64);
            e += __shfl_xor(e, 32, 64);
        }

        // ---- epilogue ----
        if (isH) {
            float add;
            if (layer == 0) {
                add = biasL;
            } else {
                const uint32_t want = preTagB + (uint32_t)t;
                bool bad = ((uint32_t)(pre >> 32) != want);
                while (__any(bad)) {
                    if (bad) {
                        pre = __hip_atomic_load(preIn + (size_t)t * 4096 + (j0 << 2) + k,
                                                __ATOMIC_RELAXED, __HIP_MEMORY_SCOPE_AGENT);
                        bad = ((uint32_t)(pre >> 32) != want);
                    }
                }
                add = __uint_as_float((uint32_t)pre);   // preact holds Wih.x + b_ih + b_hh
            }
            const float val = e + add;
            // gate nonlinearity: k&3 == 2 is the g-gate (tanh), others sigmoid
            const float av = ((lane & 3) == 2) ? ftanh(val) : fsig(val);
            const int gb = lane & ~3;
            const float iv = __shfl(av, gb + 0, 64);
            const float fv = __shfl(av, gb + 1, 64);
            const float gv = __shfl(av, gb + 2, 64);
            const float ov = __shfl(av, gb + 3, 64);
            c = __fmaf_rn(fv, c, iv * gv);
            const float h = ov * ftanh(c);
            if (lane < 8 && (lane & 3) == 0) {
                const u64 slot = ((u64)(myTagB + (uint32_t)t) << 32)
                               | (u64)__float_as_uint(h);
                const int jj = j0 + (lane >> 2);
                __hip_atomic_store(valOut + (size_t)((uint32_t)t & srcRowM) * HD + jj, slot,
                                   __ATOMIC_RELAXED, __HIP_MEMORY_SCOPE_AGENT);
                if (layer != 2)
                    __hip_atomic_store(mirOut + (size_t)t * HD + jj, slot,
                                       __ATOMIC_RELAXED, __HIP_MEMORY_SCOPE_AGENT);
            }
        } else {
            const float val = e + biasL;
            if (lane < 8) {
                const u64 slot = ((u64)(preTagB + (uint32_t)t) << 32)
                               | (u64)__float_as_uint(val);
                __hip_atomic_store(preOut + (size_t)t * 4096 + (j0 << 2) + lane,
                                   slot, __ATOMIC_RELAXED, __HIP_MEMORY_SCOPE_AGENT);
            }
        }
    }
}

__global__ __launch_bounds__(256)
void final_kernel(const float* __restrict__ w_lin,
                  const float* __restrict__ b_lin,
                  float*       __restrict__ out)
{
    __shared__ float red[256];
    const int tid = threadIdx.x;
    const u64* hrow = g_ring + (size_t)((T_STEPS - 1) & (RINGR - 1)) * HD;
    float s = 0.f;
#pragma unroll
    for (int i = 0; i < 4; ++i) {
        const int kk = tid + 256 * i;
        s += __uint_as_float((uint32_t)hrow[kk]) * w_lin[kk];
    }
    red[tid] = s;
    __syncthreads();
    for (int o = 128; o > 0; o >>= 1) {
        if (tid < o) red[tid] += red[tid + o];
        __syncthreads();
    }
    if (tid == 0) out[0] = red[0] + b_lin[0];
}

extern "C" void kernel_launch(void* const* d_in, const int* in_sizes, int n_in,
                              void* d_out, int out_size, void* d_ws, size_t ws_size,
                              hipStream_t stream)
{
    (void)in_sizes; (void)n_in; (void)out_size; (void)d_ws; (void)ws_size;

    const float* seq   = (const float*)d_in[0];
    const float* w_ih0 = (const float*)d_in[1];
    const float* w_hh0 = (const float*)d_in[2];
    const float* b_ih0 = (const float*)d_in[3];
    const float* b_hh0 = (const float*)d_in[4];
    const float* w_ih1 = (const float*)d_in[5];
    const float* w_hh1 = (const float*)d_in[6];
    const float* b_ih1 = (const float*)d_in[7];
    const float* b_hh1 = (const float*)d_in[8];
    const float* w_ih2 = (const float*)d_in[9];
    const float* w_hh2 = (const float*)d_in[10];
    const float* b_ih2 = (const float*)d_in[11];
    const float* b_hh2 = (const float*)d_in[12];
    const float* w_lin = (const float*)d_in[13];
    const float* b_lin = (const float*)d_in[14];

    // Tag hygiene (previous replay left matching tags in the h buffers).
    zero_bufs<<<dim3(2048), dim3(256), 0, stream>>>();

    // Blocks [0,192) = h-role (64/layer); [192,320) = x-role (64 for L1, L2).
    fused_scan<<<dim3(320), dim3(512), 0, stream>>>(
        seq,
        w_ih0, w_hh0, b_ih0, b_hh0,
        w_ih1, w_hh1, b_ih1, b_hh1,
        w_ih2, w_hh2, b_ih2, b_hh2);

    final_kernel<<<dim3(1), dim3(256), 0, stream>>>(w_lin, b_lin, (float*)d_out);
}

// Round 8
// 20450.627 us; speedup vs baseline: 1.3029x; 1.3029x over previous
//
#include <hip/hip_runtime.h>
#include <stdint.h>
#include <stddef.h>

// LSTMNetwork: 3-layer stacked LSTM, batch=1, T=4096, IN=64, H=1024, OUT=1.
//
// Round 16: R14-exact base (best: 22.41 ms, 5.47 us/step) + h-reader
// mirror-split. R15's 512-thr experiment regressed (26.6 ms): halving
// readers via bigger blocks doubled the barrier convoy width (8-wave
// __syncthreads) and broke scheduling granularity (occupancy 31->18%).
// Lesson: pull the reader-pressure lever WITHOUT touching block geometry.
//   Mechanism (validated R12/R14, ~4 ns per reader per hot line):
//     - R14 moved x-readers to a mirror: 256 -> 128 readers on the primary
//       h-row, -0.5 us/step.
//     - R16 splits the remaining 128 h-readers across primary + a second
//       h-mirror (bu<64 -> primary, bu>=64 -> mirror-h): 64 readers/copy.
//       Producers store each h slot 3x (primary, mirror-h, mirror-x;
//       L2: primary ring + mirror ring). Fire-and-forget, ~free.
//     - Plus R15's uncontaminated piece: h-poll s_sleep(2) backoff from
//       round 2 (x keeps s_sleep(4) from round 1).
//   Everything else byte-identical to R14: 640 x 256thr blocks, 4 waves,
//   2 units/wave, 84 VGPR + AGPR FMA shape, 64-bit tagged slots, relaxed
//   agent atomics, no fences.

#define T_STEPS 4096
#define HD      1024
#define RINGR   16
#define NBH     128

#define TAGL0 0x10000000u
#define TAGL1 0x30000000u
#define TAGL2 0x50000000u
#define TAGP1 0x70000000u
#define TAGP2 0x90000000u

typedef unsigned long long u64;
typedef uint32_t u32;

// Module .bss (~512 MB). Harness never pokes these.
__device__ u64 g_bufA[(size_t)T_STEPS * HD];    // layer0 h history (32 MB)
__device__ u64 g_bufB[(size_t)T_STEPS * HD];    // layer1 h history (32 MB)
__device__ u64 g_ring[RINGR * HD];              // layer2 h ring (128 KB)
__device__ u64 g_mhA[(size_t)T_STEPS * HD];     // layer0 h mirror for h-readers bu>=64 (32 MB)
__device__ u64 g_mhB[(size_t)T_STEPS * HD];     // layer1 h mirror for h-readers bu>=64 (32 MB)
__device__ u64 g_ring2[RINGR * HD];             // layer2 h mirror ring (128 KB)
__device__ u64 g_mirA[(size_t)T_STEPS * HD];    // layer0 h mirror for x-readers (32 MB)
__device__ u64 g_mirB[(size_t)T_STEPS * HD];    // layer1 h mirror for x-readers (32 MB)
__device__ u64 g_pre1[(size_t)T_STEPS * 4096];  // layer1 gate preacts (128 MB)
__device__ u64 g_pre2[(size_t)T_STEPS * 4096];  // layer2 gate preacts (128 MB)

__device__ __forceinline__ float fsig(float x)  { return 1.0f / (1.0f + __expf(-x)); }
__device__ __forceinline__ float ftanh(float x) { return 1.0f - 2.0f / (__expf(2.0f * x) + 1.0f); }

__global__ __launch_bounds__(256)
void zero_bufs()
{
    const size_t gtid = (size_t)blockIdx.x * blockDim.x + threadIdx.x;
    const size_t step = (size_t)gridDim.x * blockDim.x;
    const size_t nh = (size_t)T_STEPS * HD;
    for (size_t i = gtid; i < nh; i += step) {
        g_bufA[i] = 0ULL; g_bufB[i] = 0ULL;
        g_mhA[i]  = 0ULL; g_mhB[i]  = 0ULL;
        g_mirA[i] = 0ULL; g_mirB[i] = 0ULL;
    }
    for (size_t i = gtid; i < (size_t)RINGR * HD; i += step) {
        g_ring[i] = 0ULL; g_ring2[i] = 0ULL;
    }
}

__global__ __launch_bounds__(256, 3)   // 640 blocks, 3 blocks/CU cap => all co-resident
void fused_scan(const float* __restrict__ seq,
                const float* __restrict__ wih0, const float* __restrict__ whh0_,
                const float* __restrict__ bih0, const float* __restrict__ bhh0,
                const float* __restrict__ wih1, const float* __restrict__ whh1_,
                const float* __restrict__ bih1, const float* __restrict__ bhh1,
                const float* __restrict__ wih2, const float* __restrict__ whh2_,
                const float* __restrict__ bih2, const float* __restrict__ bhh2)
{
    __shared__ float s_buf[2][HD];   // staged source row (own-h for h-role, upstream-h for x-role)

    const int bid  = blockIdx.x;
    const int lane = threadIdx.x & 63;
    const int wave = threadIdx.x >> 6;

    const bool isH  = (bid < 3 * NBH);
    const int layer = isH ? (bid >> 7) : (1 + ((bid - 3 * NBH) >> 7));
    const int bu    = isH ? (bid & (NBH - 1)) : ((bid - 3 * NBH) & (NBH - 1));
    const int j0    = bu * 8 + wave * 2;       // first of this wave's 2 units
    const int k     = lane & 7;                // acc index this lane finalizes (u*4+g)
    const int rk    = ((k & 3) << 10) + j0 + (k >> 2);   // its gate-row in [4H]

    // ---- role pointers ----
    const float* Wmat;
    const u64*  srcVal;  uint32_t srcTagB, srcRowM = 0xFFFFFFFFu;
    u64*        valOut = nullptr;   u64* mhOut = nullptr;   u64* mirOut = nullptr;
    u64*        preOut = nullptr;
    const u64*  preIn  = nullptr;
    uint32_t    myTagB = 0, preTagB = 0;
    float       biasL  = 0.f;

    if (isH) {
        Wmat    = (layer == 0) ? whh0_ : (layer == 1) ? whh1_ : whh2_;
        valOut  = (layer == 0) ? g_bufA : (layer == 1) ? g_bufB : g_ring;
        mhOut   = (layer == 0) ? g_mhA  : (layer == 1) ? g_mhB  : g_ring2;
        mirOut  = (layer == 0) ? g_mirA : (layer == 1) ? g_mirB : nullptr;
        myTagB  = (layer == 0) ? TAGL0 : (layer == 1) ? TAGL1 : TAGL2;
        srcRowM = (layer == 2) ? (RINGR - 1) : 0xFFFFFFFFu;
        srcVal  = (bu < 64) ? valOut : mhOut;   // reader split: 64 readers/copy
        srcTagB = myTagB;
        if (layer == 1) { preIn = g_pre1; preTagB = TAGP1; }
        if (layer == 2) { preIn = g_pre2; preTagB = TAGP2; }
        if (layer == 0) biasL = bih0[rk] + bhh0[rk];
    } else {
        Wmat    = (layer == 1) ? wih1 : wih2;
        srcVal  = (layer == 1) ? g_mirA : g_mirB;          // x reads the x-mirror
        srcTagB = (layer == 1) ? TAGL0 : TAGL1;
        preOut  = (layer == 1) ? g_pre1 : g_pre2;
        preTagB = (layer == 1) ? TAGP1 : TAGP2;
        biasL   = (layer == 1) ? (bih1[rk] + bhh1[rk]) : (bih2[rk] + bhh2[rk]);
    }

    // ---- weights into registers: 8 gate-rows (2 units x 4 gates) x 16 ----
    float W[8][16];
#pragma unroll
    for (int u = 0; u < 2; ++u)
#pragma unroll
        for (int g = 0; g < 4; ++g) {
            const float* pr = Wmat + (size_t)((g << 10) + j0 + u) * HD;
#pragma unroll
            for (int i = 0; i < 16; ++i) W[u * 4 + g][i] = pr[(i << 6) + lane];
        }

    float wi0[8];
    if (isH && layer == 0) {
#pragma unroll
        for (int kk = 0; kk < 8; ++kk)
            wi0[kk] = wih0[(size_t)(((kk & 3) << 10) + j0 + (kk >> 2)) * 64 + lane];
    }

    float c = 0.f;
    const int sb = wave << 8;    // this wave's staging quarter [sb, sb+256)

    for (int t = 0; t < T_STEPS; ++t) {
        const int p = t & 1;
        u64 pre = 0; float xv = 0.f;
        const bool needRow = (!isH) || (t > 0);

        // ---- early preact probe (one line, >=1 pipeline slot of slack) ----
        if (isH) {
            if (layer == 0) {
                xv = seq[(size_t)t * 64 + lane];
            } else {
                pre = __hip_atomic_load(preIn + (size_t)t * 4096 + (j0 << 2) + k,
                                        __ATOMIC_RELAXED, __HIP_MEMORY_SCOPE_AGENT);
            }
        }

        // ---- staging: poll own quarter of source row, stage incrementally ----
        if (needRow) {
            const uint32_t stag = srcTagB + (uint32_t)(isH ? (t - 1) : t);
            const u64* rowp = srcVal
                + (size_t)((uint32_t)(isH ? (t - 1) : t) & srcRowM) * HD;
            u32 todo = 0xFu;
            int round = 0;
            while (__any(todo)) {
                if (!isH) { if (round >= 1) __builtin_amdgcn_s_sleep(4); }   // ~107ns
                else      { if (round >= 2) __builtin_amdgcn_s_sleep(2); }   // ~53ns
#pragma unroll
                for (int i = 0; i < 4; ++i) if (todo & (1u << i)) {
                    const u64 u = __hip_atomic_load(rowp + sb + (i << 6) + lane,
                                                    __ATOMIC_RELAXED, __HIP_MEMORY_SCOPE_AGENT);
                    if ((uint32_t)(u >> 32) == stag) {
                        s_buf[p][sb + (i << 6) + lane] = __uint_as_float((uint32_t)u);
                        todo &= ~(1u << i);
                    }
                }
                ++round;
            }
        }
        __syncthreads();

        // ---- 8 gate dot-products (per-lane partials) ----
        float a0, a1, a2, a3, a4, a5, a6, a7;
        if (isH && layer == 0) {
            a0 = wi0[0] * xv; a1 = wi0[1] * xv; a2 = wi0[2] * xv; a3 = wi0[3] * xv;
            a4 = wi0[4] * xv; a5 = wi0[5] * xv; a6 = wi0[6] * xv; a7 = wi0[7] * xv;
        } else {
            a0 = a1 = a2 = a3 = a4 = a5 = a6 = a7 = 0.f;
        }
        if (needRow) {
            const float* sp = s_buf[p];
#pragma unroll
            for (int i = 0; i < 16; ++i) {
                const float hv = sp[(i << 6) | lane];
                a0 = __fmaf_rn(W[0][i], hv, a0);
                a1 = __fmaf_rn(W[1][i], hv, a1);
                a2 = __fmaf_rn(W[2][i], hv, a2);
                a3 = __fmaf_rn(W[3][i], hv, a3);
                a4 = __fmaf_rn(W[4][i], hv, a4);
                a5 = __fmaf_rn(W[5][i], hv, a5);
                a6 = __fmaf_rn(W[6][i], hv, a6);
                a7 = __fmaf_rn(W[7][i], hv, a7);
            }
        }

        // ---- scatter-butterfly reduce: lane l ends with 64-lane sum of acc (l&7) ----
        float e;
        {
            const int l1 = lane & 1, l2 = lane & 2, l4 = lane & 4;
            const float s0 = __shfl_xor(a0, 1, 64), s1 = __shfl_xor(a1, 1, 64);
            const float s2 = __shfl_xor(a2, 1, 64), s3 = __shfl_xor(a3, 1, 64);
            const float s4 = __shfl_xor(a4, 1, 64), s5 = __shfl_xor(a5, 1, 64);
            const float s6 = __shfl_xor(a6, 1, 64), s7 = __shfl_xor(a7, 1, 64);
            const float c0 = l1 ? (a1 + s1) : (a0 + s0);
            const float c1 = l1 ? (a3 + s3) : (a2 + s2);
            const float c2 = l1 ? (a5 + s5) : (a4 + s4);
            const float c3 = l1 ? (a7 + s7) : (a6 + s6);
            const float u0 = __shfl_xor(c0, 2, 64), u1 = __shfl_xor(c1, 2, 64);
            const float u2 = __shfl_xor(c2, 2, 64), u3 = __shfl_xor(c3, 2, 64);
            const float d0 = l2 ? (c1 + u1) : (c0 + u0);
            const float d1 = l2 ? (c3 + u3) : (c2 + u2);
            const float v0 = __shfl_xor(d0, 4, 64), v1 = __shfl_xor(d1, 4, 64);
            e = l4 ? (d1 + v1) : (d0 + v0);
            e += __shfl_xor(e, 8, 64);
            e += __shfl_xor(e, 16, 64);
            e += __shfl_xor(e, 32, 64);
        }

        // ---- epilogue ----
        if (isH) {
            float add;
            if (layer == 0) {
                add = biasL;
            } else {
                const uint32_t want = preTagB + (uint32_t)t;
                bool bad = ((uint32_t)(pre >> 32) != want);
                while (__any(bad)) {
                    if (bad) {
                        pre = __hip_atomic_load(preIn + (size_t)t * 4096 + (j0 << 2) + k,
                                                __ATOMIC_RELAXED, __HIP_MEMORY_SCOPE_AGENT);
                        bad = ((uint32_t)(pre >> 32) != want);
                    }
                }
                add = __uint_as_float((uint32_t)pre);   // preact holds Wih.x + b_ih + b_hh
            }
            const float val = e + add;
            // gate nonlinearity: k&3 == 2 is the g-gate (tanh), others sigmoid
            const float av = ((lane & 3) == 2) ? ftanh(val) : fsig(val);
            const int gb = lane & ~3;
            const float iv = __shfl(av, gb + 0, 64);
            const float fv = __shfl(av, gb + 1, 64);
            const float gv = __shfl(av, gb + 2, 64);
            const float ov = __shfl(av, gb + 3, 64);
            c = __fmaf_rn(fv, c, iv * gv);
            const float h = ov * ftanh(c);
            if (lane < 8 && (lane & 3) == 0) {
                const u64 slot = ((u64)(myTagB + (uint32_t)t) << 32)
                               | (u64)__float_as_uint(h);
                const int jj = j0 + (lane >> 2);
                const size_t roff = (size_t)((uint32_t)t & srcRowM) * HD + jj;
                __hip_atomic_store(valOut + roff, slot,
                                   __ATOMIC_RELAXED, __HIP_MEMORY_SCOPE_AGENT);
                __hip_atomic_store(mhOut + roff, slot,
                                   __ATOMIC_RELAXED, __HIP_MEMORY_SCOPE_AGENT);
                if (layer != 2)
                    __hip_atomic_store(mirOut + (size_t)t * HD + jj, slot,
                                       __ATOMIC_RELAXED, __HIP_MEMORY_SCOPE_AGENT);
            }
        } else {
            const float val = e + biasL;
            if (lane < 8) {
                const u64 slot = ((u64)(preTagB + (uint32_t)t) << 32)
                               | (u64)__float_as_uint(val);
                __hip_atomic_store(preOut + (size_t)t * 4096 + (j0 << 2) + lane,
                                   slot, __ATOMIC_RELAXED, __HIP_MEMORY_SCOPE_AGENT);
            }
        }
    }
}

__global__ __launch_bounds__(256)
void final_kernel(const float* __restrict__ w_lin,
                  const float* __restrict__ b_lin,
                  float*       __restrict__ out)
{
    __shared__ float red[256];
    const int tid = threadIdx.x;
    const u64* hrow = g_ring + (size_t)((T_STEPS - 1) & (RINGR - 1)) * HD;
    float s = 0.f;
#pragma unroll
    for (int i = 0; i < 4; ++i) {
        const int kk = tid + 256 * i;
        s += __uint_as_float((uint32_t)hrow[kk]) * w_lin[kk];
    }
    red[tid] = s;
    __syncthreads();
    for (int o = 128; o > 0; o >>= 1) {
        if (tid < o) red[tid] += red[tid + o];
        __syncthreads();
    }
    if (tid == 0) out[0] = red[0] + b_lin[0];
}

extern "C" void kernel_launch(void* const* d_in, const int* in_sizes, int n_in,
                              void* d_out, int out_size, void* d_ws, size_t ws_size,
                              hipStream_t stream)
{
    (void)in_sizes; (void)n_in; (void)out_size; (void)d_ws; (void)ws_size;

    const float* seq   = (const float*)d_in[0];
    const float* w_ih0 = (const float*)d_in[1];
    const float* w_hh0 = (const float*)d_in[2];
    const float* b_ih0 = (const float*)d_in[3];
    const float* b_hh0 = (const float*)d_in[4];
    const float* w_ih1 = (const float*)d_in[5];
    const float* w_hh1 = (const float*)d_in[6];
    const float* b_ih1 = (const float*)d_in[7];
    const float* b_hh1 = (const float*)d_in[8];
    const float* w_ih2 = (const float*)d_in[9];
    const float* w_hh2 = (const float*)d_in[10];
    const float* b_ih2 = (const float*)d_in[11];
    const float* b_hh2 = (const float*)d_in[12];
    const float* w_lin = (const float*)d_in[13];
    const float* b_lin = (const float*)d_in[14];

    // Tag hygiene (previous replay left matching tags in the h buffers).
    zero_bufs<<<dim3(2048), dim3(256), 0, stream>>>();

    // Blocks [0,384) = h-role (128/layer); [384,640) = x-role (128 for L1, L2).
    fused_scan<<<dim3(640), dim3(256), 0, stream>>>(
        seq,
        w_ih0, w_hh0, b_ih0, b_hh0,
        w_ih1, w_hh1, b_ih1, b_hh1,
        w_ih2, w_hh2, b_ih2, b_hh2);

    final_kernel<<<dim3(1), dim3(256), 0, stream>>>(w_lin, b_lin, (float*)d_out);
}

// Round 9
// 19681.021 us; speedup vs baseline: 1.3538x; 1.0391x over previous
//
#include <hip/hip_runtime.h>
#include <stdint.h>
#include <stddef.h>

// LSTMNetwork: 3-layer stacked LSTM, batch=1, T=4096, IN=64, H=1024, OUT=1.
//
// Round 17: R16-exact base (best: 20.45 ms, 4.99 us/step) + next stop on the
// reader-split lever. Mechanism validated 3x (R12/R14/R16, ~4-8 ns per
// reader removed from a hot copy; producer-side replication measured ~free):
//   - 4-way h-reader split: 128 h-blocks/layer -> copy bu>>5, 32 readers/copy
//     (was 2-way, 64).
//   - 2-way x-reader split: 128 x-blocks/layer -> copy bu>>6, 64 readers/copy
//     (was 1 copy, 128). x-lag is pipeline slack, but x-polls add to total
//     LLC pressure (the systemic variable).
//   - Producers (lanes 0/4) fire-and-forget 6 stores/slot (L0/L1: 4 h + 2 x;
//     L2: 4 ring copies). Off the critical path.
//   Wave code, FMA shape (84 VGPR + AGPR), poll structure, backoffs
//   (h: s_sleep(2) from round 2; x: s_sleep(4) from round 1), barriers:
//   byte-identical to R16. Geometry untouched (R15 lesson).
//   Exchange: 64-bit tagged slots, relaxed agent atomics, no fences.

#define T_STEPS 4096
#define HD      1024
#define RINGR   16
#define NBH     128

#define TAGL0 0x10000000u
#define TAGL1 0x30000000u
#define TAGL2 0x50000000u
#define TAGP1 0x70000000u
#define TAGP2 0x90000000u

typedef unsigned long long u64;
typedef uint32_t u32;

// Module .bss (~640 MB). Harness never pokes these.
__device__ u64 g_hL0[4][(size_t)T_STEPS * HD];  // layer0 h history x4 replicas (128 MB)
__device__ u64 g_hL1[4][(size_t)T_STEPS * HD];  // layer1 h history x4 replicas (128 MB)
__device__ u64 g_hL2[4][RINGR * HD];            // layer2 h ring x4 replicas (512 KB)
__device__ u64 g_mx0[2][(size_t)T_STEPS * HD];  // layer0 h mirrors for x-readers (64 MB)
__device__ u64 g_mx1[2][(size_t)T_STEPS * HD];  // layer1 h mirrors for x-readers (64 MB)
__device__ u64 g_pre1[(size_t)T_STEPS * 4096];  // layer1 gate preacts (128 MB)
__device__ u64 g_pre2[(size_t)T_STEPS * 4096];  // layer2 gate preacts (128 MB)

__device__ __forceinline__ float fsig(float x)  { return 1.0f / (1.0f + __expf(-x)); }
__device__ __forceinline__ float ftanh(float x) { return 1.0f - 2.0f / (__expf(2.0f * x) + 1.0f); }

__global__ __launch_bounds__(256)
void zero_bufs()
{
    const size_t gtid = (size_t)blockIdx.x * blockDim.x + threadIdx.x;
    const size_t step = (size_t)gridDim.x * blockDim.x;
    const size_t nh = (size_t)T_STEPS * HD;
    for (size_t i = gtid; i < nh; i += step) {
#pragma unroll
        for (int r = 0; r < 4; ++r) { g_hL0[r][i] = 0ULL; g_hL1[r][i] = 0ULL; }
#pragma unroll
        for (int r = 0; r < 2; ++r) { g_mx0[r][i] = 0ULL; g_mx1[r][i] = 0ULL; }
    }
    for (size_t i = gtid; i < (size_t)RINGR * HD; i += step) {
#pragma unroll
        for (int r = 0; r < 4; ++r) g_hL2[r][i] = 0ULL;
    }
}

__global__ __launch_bounds__(256, 3)   // 640 blocks, 3 blocks/CU cap => all co-resident
void fused_scan(const float* __restrict__ seq,
                const float* __restrict__ wih0, const float* __restrict__ whh0_,
                const float* __restrict__ bih0, const float* __restrict__ bhh0,
                const float* __restrict__ wih1, const float* __restrict__ whh1_,
                const float* __restrict__ bih1, const float* __restrict__ bhh1,
                const float* __restrict__ wih2, const float* __restrict__ whh2_,
                const float* __restrict__ bih2, const float* __restrict__ bhh2)
{
    __shared__ float s_buf[2][HD];   // staged source row (own-h for h-role, upstream-h for x-role)

    const int bid  = blockIdx.x;
    const int lane = threadIdx.x & 63;
    const int wave = threadIdx.x >> 6;

    const bool isH  = (bid < 3 * NBH);
    const int layer = isH ? (bid >> 7) : (1 + ((bid - 3 * NBH) >> 7));
    const int bu    = isH ? (bid & (NBH - 1)) : ((bid - 3 * NBH) & (NBH - 1));
    const int j0    = bu * 8 + wave * 2;       // first of this wave's 2 units
    const int k     = lane & 7;                // acc index this lane finalizes (u*4+g)
    const int rk    = ((k & 3) << 10) + j0 + (k >> 2);   // its gate-row in [4H]

    // ---- role pointers ----
    const float* Wmat;
    const u64*  srcVal;  uint32_t srcTagB, srcRowM = 0xFFFFFFFFu;
    u64*        hOut0 = nullptr; u64* hOut1 = nullptr; u64* hOut2 = nullptr; u64* hOut3 = nullptr;
    u64*        xOut0 = nullptr; u64* xOut1 = nullptr;
    u64*        preOut = nullptr;
    const u64*  preIn  = nullptr;
    uint32_t    myTagB = 0, preTagB = 0;
    float       biasL  = 0.f;

    if (isH) {
        Wmat    = (layer == 0) ? whh0_ : (layer == 1) ? whh1_ : whh2_;
        myTagB  = (layer == 0) ? TAGL0 : (layer == 1) ? TAGL1 : TAGL2;
        srcRowM = (layer == 2) ? (RINGR - 1) : 0xFFFFFFFFu;
        if (layer == 0) {
            hOut0 = g_hL0[0]; hOut1 = g_hL0[1]; hOut2 = g_hL0[2]; hOut3 = g_hL0[3];
            xOut0 = g_mx0[0]; xOut1 = g_mx0[1];
        } else if (layer == 1) {
            hOut0 = g_hL1[0]; hOut1 = g_hL1[1]; hOut2 = g_hL1[2]; hOut3 = g_hL1[3];
            xOut0 = g_mx1[0]; xOut1 = g_mx1[1];
        } else {
            hOut0 = g_hL2[0]; hOut1 = g_hL2[1]; hOut2 = g_hL2[2]; hOut3 = g_hL2[3];
        }
        // reader split: 4 replicas, 32 readers each
        srcVal  = (bu < 32) ? hOut0 : (bu < 64) ? hOut1 : (bu < 96) ? hOut2 : hOut3;
        srcTagB = myTagB;
        if (layer == 1) { preIn = g_pre1; preTagB = TAGP1; }
        if (layer == 2) { preIn = g_pre2; preTagB = TAGP2; }
        if (layer == 0) biasL = bih0[rk] + bhh0[rk];
    } else {
        Wmat    = (layer == 1) ? wih1 : wih2;
        srcVal  = (layer == 1) ? g_mx0[bu >> 6] : g_mx1[bu >> 6];   // 2-way x split
        srcTagB = (layer == 1) ? TAGL0 : TAGL1;
        preOut  = (layer == 1) ? g_pre1 : g_pre2;
        preTagB = (layer == 1) ? TAGP1 : TAGP2;
        biasL   = (layer == 1) ? (bih1[rk] + bhh1[rk]) : (bih2[rk] + bhh2[rk]);
    }

    // ---- weights into registers: 8 gate-rows (2 units x 4 gates) x 16 ----
    float W[8][16];
#pragma unroll
    for (int u = 0; u < 2; ++u)
#pragma unroll
        for (int g = 0; g < 4; ++g) {
            const float* pr = Wmat + (size_t)((g << 10) + j0 + u) * HD;
#pragma unroll
            for (int i = 0; i < 16; ++i) W[u * 4 + g][i] = pr[(i << 6) + lane];
        }

    float wi0[8];
    if (isH && layer == 0) {
#pragma unroll
        for (int kk = 0; kk < 8; ++kk)
            wi0[kk] = wih0[(size_t)(((kk & 3) << 10) + j0 + (kk >> 2)) * 64 + lane];
    }

    float c = 0.f;
    const int sb = wave << 8;    // this wave's staging quarter [sb, sb+256)

    for (int t = 0; t < T_STEPS; ++t) {
        const int p = t & 1;
        u64 pre = 0; float xv = 0.f;
        const bool needRow = (!isH) || (t > 0);

        // ---- early preact probe (one line, >=1 pipeline slot of slack) ----
        if (isH) {
            if (layer == 0) {
                xv = seq[(size_t)t * 64 + lane];
            } else {
                pre = __hip_atomic_load(preIn + (size_t)t * 4096 + (j0 << 2) + k,
                                        __ATOMIC_RELAXED, __HIP_MEMORY_SCOPE_AGENT);
            }
        }

        // ---- staging: poll own quarter of source row, stage incrementally ----
        if (needRow) {
            const uint32_t stag = srcTagB + (uint32_t)(isH ? (t - 1) : t);
            const u64* rowp = srcVal
                + (size_t)((uint32_t)(isH ? (t - 1) : t) & srcRowM) * HD;
            u32 todo = 0xFu;
            int round = 0;
            while (__any(todo)) {
                if (!isH) { if (round >= 1) __builtin_amdgcn_s_sleep(4); }   // ~107ns
                else      { if (round >= 2) __builtin_amdgcn_s_sleep(2); }   // ~53ns
#pragma unroll
                for (int i = 0; i < 4; ++i) if (todo & (1u << i)) {
                    const u64 u = __hip_atomic_load(rowp + sb + (i << 6) + lane,
                                                    __ATOMIC_RELAXED, __HIP_MEMORY_SCOPE_AGENT);
                    if ((uint32_t)(u >> 32) == stag) {
                        s_buf[p][sb + (i << 6) + lane] = __uint_as_float((uint32_t)u);
                        todo &= ~(1u << i);
                    }
                }
                ++round;
            }
        }
        __syncthreads();

        // ---- 8 gate dot-products (per-lane partials) ----
        float a0, a1, a2, a3, a4, a5, a6, a7;
        if (isH && layer == 0) {
            a0 = wi0[0] * xv; a1 = wi0[1] * xv; a2 = wi0[2] * xv; a3 = wi0[3] * xv;
            a4 = wi0[4] * xv; a5 = wi0[5] * xv; a6 = wi0[6] * xv; a7 = wi0[7] * xv;
        } else {
            a0 = a1 = a2 = a3 = a4 = a5 = a6 = a7 = 0.f;
        }
        if (needRow) {
            const float* sp = s_buf[p];
#pragma unroll
            for (int i = 0; i < 16; ++i) {
                const float hv = sp[(i << 6) | lane];
                a0 = __fmaf_rn(W[0][i], hv, a0);
                a1 = __fmaf_rn(W[1][i], hv, a1);
                a2 = __fmaf_rn(W[2][i], hv, a2);
                a3 = __fmaf_rn(W[3][i], hv, a3);
                a4 = __fmaf_rn(W[4][i], hv, a4);
                a5 = __fmaf_rn(W[5][i], hv, a5);
                a6 = __fmaf_rn(W[6][i], hv, a6);
                a7 = __fmaf_rn(W[7][i], hv, a7);
            }
        }

        // ---- scatter-butterfly reduce: lane l ends with 64-lane sum of acc (l&7) ----
        float e;
        {
            const int l1 = lane & 1, l2 = lane & 2, l4 = lane & 4;
            const float s0 = __shfl_xor(a0, 1, 64), s1 = __shfl_xor(a1, 1, 64);
            const float s2 = __shfl_xor(a2, 1, 64), s3 = __shfl_xor(a3, 1, 64);
            const float s4 = __shfl_xor(a4, 1, 64), s5 = __shfl_xor(a5, 1, 64);
            const float s6 = __shfl_xor(a6, 1, 64), s7 = __shfl_xor(a7, 1, 64);
            const float c0 = l1 ? (a1 + s1) : (a0 + s0);
            const float c1 = l1 ? (a3 + s3) : (a2 + s2);
            const float c2 = l1 ? (a5 + s5) : (a4 + s4);
            const float c3 = l1 ? (a7 + s7) : (a6 + s6);
            const float u0 = __shfl_xor(c0, 2, 64), u1 = __shfl_xor(c1, 2, 64);
            const float u2 = __shfl_xor(c2, 2, 64), u3 = __shfl_xor(c3, 2, 64);
            const float d0 = l2 ? (c1 + u1) : (c0 + u0);
            const float d1 = l2 ? (c3 + u3) : (c2 + u2);
            const float v0 = __shfl_xor(d0, 4, 64), v1 = __shfl_xor(d1, 4, 64);
            e = l4 ? (d1 + v1) : (d0 + v0);
            e += __shfl_xor(e, 8, 64);
            e += __shfl_xor(e, 16, 64);
            e += __shfl_xor(e, 32, 64);
        }

        // ---- epilogue ----
        if (isH) {
            float add;
            if (layer == 0) {
                add = biasL;
            } else {
                const uint32_t want = preTagB + (uint32_t)t;
                bool bad = ((uint32_t)(pre >> 32) != want);
                while (__any(bad)) {
                    if (bad) {
                        pre = __hip_atomic_load(preIn + (size_t)t * 4096 + (j0 << 2) + k,
                                                __ATOMIC_RELAXED, __HIP_MEMORY_SCOPE_AGENT);
                        bad = ((uint32_t)(pre >> 32) != want);
                    }
                }
                add = __uint_as_float((uint32_t)pre);   // preact holds Wih.x + b_ih + b_hh
            }
            const float val = e + add;
            // gate nonlinearity: k&3 == 2 is the g-gate (tanh), others sigmoid
            const float av = ((lane & 3) == 2) ? ftanh(val) : fsig(val);
            const int gb = lane & ~3;
            const float iv = __shfl(av, gb + 0, 64);
            const float fv = __shfl(av, gb + 1, 64);
            const float gv = __shfl(av, gb + 2, 64);
            const float ov = __shfl(av, gb + 3, 64);
            c = __fmaf_rn(fv, c, iv * gv);
            const float h = ov * ftanh(c);
            if (lane < 8 && (lane & 3) == 0) {
                const u64 slot = ((u64)(myTagB + (uint32_t)t) << 32)
                               | (u64)__float_as_uint(h);
                const int jj = j0 + (lane >> 2);
                const size_t roff = (size_t)((uint32_t)t & srcRowM) * HD + jj;
                __hip_atomic_store(hOut0 + roff, slot, __ATOMIC_RELAXED, __HIP_MEMORY_SCOPE_AGENT);
                __hip_atomic_store(hOut1 + roff, slot, __ATOMIC_RELAXED, __HIP_MEMORY_SCOPE_AGENT);
                __hip_atomic_store(hOut2 + roff, slot, __ATOMIC_RELAXED, __HIP_MEMORY_SCOPE_AGENT);
                __hip_atomic_store(hOut3 + roff, slot, __ATOMIC_RELAXED, __HIP_MEMORY_SCOPE_AGENT);
                if (layer != 2) {
                    const size_t xoff = (size_t)t * HD + jj;
                    __hip_atomic_store(xOut0 + xoff, slot, __ATOMIC_RELAXED, __HIP_MEMORY_SCOPE_AGENT);
                    __hip_atomic_store(xOut1 + xoff, slot, __ATOMIC_RELAXED, __HIP_MEMORY_SCOPE_AGENT);
                }
            }
        } else {
            const float val = e + biasL;
            if (lane < 8) {
                const u64 slot = ((u64)(preTagB + (uint32_t)t) << 32)
                               | (u64)__float_as_uint(val);
                __hip_atomic_store(preOut + (size_t)t * 4096 + (j0 << 2) + lane,
                                   slot, __ATOMIC_RELAXED, __HIP_MEMORY_SCOPE_AGENT);
            }
        }
    }
}

__global__ __launch_bounds__(256)
void final_kernel(const float* __restrict__ w_lin,
                  const float* __restrict__ b_lin,
                  float*       __restrict__ out)
{
    __shared__ float red[256];
    const int tid = threadIdx.x;
    const u64* hrow = g_hL2[0] + (size_t)((T_STEPS - 1) & (RINGR - 1)) * HD;
    float s = 0.f;
#pragma unroll
    for (int i = 0; i < 4; ++i) {
        const int kk = tid + 256 * i;
        s += __uint_as_float((uint32_t)hrow[kk]) * w_lin[kk];
    }
    red[tid] = s;
    __syncthreads();
    for (int o = 128; o > 0; o >>= 1) {
        if (tid < o) red[tid] += red[tid + o];
        __syncthreads();
    }
    if (tid == 0) out[0] = red[0] + b_lin[0];
}

extern "C" void kernel_launch(void* const* d_in, const int* in_sizes, int n_in,
                              void* d_out, int out_size, void* d_ws, size_t ws_size,
                              hipStream_t stream)
{
    (void)in_sizes; (void)n_in; (void)out_size; (void)d_ws; (void)ws_size;

    const float* seq   = (const float*)d_in[0];
    const float* w_ih0 = (const float*)d_in[1];
    const float* w_hh0 = (const float*)d_in[2];
    const float* b_ih0 = (const float*)d_in[3];
    const float* b_hh0 = (const float*)d_in[4];
    const float* w_ih1 = (const float*)d_in[5];
    const float* w_hh1 = (const float*)d_in[6];
    const float* b_ih1 = (const float*)d_in[7];
    const float* b_hh1 = (const float*)d_in[8];
    const float* w_ih2 = (const float*)d_in[9];
    const float* w_hh2 = (const float*)d_in[10];
    const float* b_ih2 = (const float*)d_in[11];
    const float* b_hh2 = (const float*)d_in[12];
    const float* w_lin = (const float*)d_in[13];
    const float* b_lin = (const float*)d_in[14];

    // Tag hygiene (previous replay left matching tags in the h buffers).
    zero_bufs<<<dim3(2048), dim3(256), 0, stream>>>();

    // Blocks [0,384) = h-role (128/layer); [384,640) = x-role (128 for L1, L2).
    fused_scan<<<dim3(640), dim3(256), 0, stream>>>(
        seq,
        w_ih0, w_hh0, b_ih0, b_hh0,
        w_ih1, w_hh1, b_ih1, b_hh1,
        w_ih2, w_hh2, b_ih2, b_hh2);

    final_kernel<<<dim3(1), dim3(256), 0, stream>>>(w_lin, b_lin, (float*)d_out);
}